// Round 6
// baseline (54.027 us; speedup 1.0000x reference)
//
#include <hip/hip_runtime.h>

typedef __attribute__((ext_vector_type(8))) short short8;
typedef __attribute__((ext_vector_type(4))) float f32x4;
typedef unsigned int uint32;

namespace {
constexpr int F = 512, NB = 4096;
constexpr int RB = 1024;         // rows per block (and per wave)
constexpr int FPB = 4;           // features per block = waves per block
constexpr int NFQ = F / FPB;     // 128 feature-quads
// workspace layout
constexpr size_t OFF_W1F  = 0;                                   // F*4*64*16B = 2 MB
constexpr size_t OFF_W2F  = OFF_W1F + (size_t)F * 4 * 64 * 16;   // 2 MB
constexpr size_t OFF_TAB  = OFF_W2F + (size_t)F * 4 * 64 * 16;   // F*160*4 = 320 KB
constexpr size_t OFF_PART = OFF_TAB + (size_t)F * 160 * 4;       // NFQ*NB*4 = 2 MB
constexpr size_t WS_NEED  = OFF_PART + (size_t)NFQ * NB * 4;     // ~6.3 MB
}

__device__ __forceinline__ uint32 cvtpk(float lo, float hi) { // packed bf16 pair (RNE)
    uint32 r;
    asm("v_cvt_pk_bf16_f32 %0, %1, %2" : "=v"(r) : "v"(lo), "v"(hi));
    return r;
}
__device__ __forceinline__ float clip01(float v) {
    return __builtin_amdgcn_fmed3f(v, 0.f, 1.f);
}

// ---------- K0: prep — per-feature tables (pre-negated/permuted) + bf16 frag images ----------
// pi(j): j=[b5 b4 b3 b2 b1 b0] -> [b4 b3 b2 b5 b1 b0]; W1 A-frag columns pre-permuted so
// layer-1 D-registers are directly layer-2 B-fragments (no LDS transpose in main).
// tab layout per f (160 f32): [0:32) A | [32:64) -C | [64:128) -d1 (pi-permuted) | [128:160) -d2
__global__ __launch_bounds__(256) void nam_prep(
    const float* __restrict__ W0, const float* __restrict__ b0,
    const float* __restrict__ W1, const float* __restrict__ b1,
    const float* __restrict__ W2, const float* __restrict__ b2,
    char* __restrict__ ws)
{
    const int f = blockIdx.x;
    const int t = threadIdx.x;
    const int lane = t & 63, w = t >> 6, g = lane >> 4, rr = lane & 15;

    __shared__ float LW[2048];
    __shared__ float red[256], red2[256];

    const float* W0f = W0 + (size_t)f * 1024;
    const float* W1f = W1 + (size_t)f * 2048;
    const float* W2f = W2 + (size_t)f * 2048;
    float* tab = (float*)(ws + OFF_TAB) + (size_t)f * 160;
    union U8 { uint32 u[4]; short8 s8; };

    // ---- phase 0: W0 -> A, -C ----
    *(float4*)&LW[t * 4] = *(const float4*)&W0f[t * 4];
    __syncthreads();
    {
        int j = t & 31, sc = t >> 5;
        float a = 0.f, c = 0.f;
#pragma unroll
        for (int k = 0; k < 4; ++k) {
            int s = sc * 4 + k;
            float e = expf(LW[s * 32 + j]);
            a += e; c += b0[f * 32 + s] * e;
        }
        red[sc * 32 + j] = a; red2[sc * 32 + j] = c;
    }
    __syncthreads();
    if (t < 32) {
        float a = 0.f, c = 0.f;
#pragma unroll
        for (int k = 0; k < 8; ++k) { a += red[k * 32 + t]; c += red2[k * 32 + t]; }
        tab[t] = a; tab[32 + t] = -c;
    }
    __syncthreads();

    // ---- phase 1: W1 -> -d1 (permuted), w1 frag image ----
    *(float4*)&LW[t * 4]        = *(const float4*)&W1f[t * 4];
    *(float4*)&LW[1024 + t * 4] = *(const float4*)&W1f[1024 + t * 4];
    __syncthreads();
    {
        int j = t & 63, sc = t >> 6;
        float d = 0.f;
#pragma unroll
        for (int k = 0; k < 8; ++k) {
            int s = sc * 8 + k;
            d += b1[f * 32 + s] * LW[s * 64 + j];
        }
        red[sc * 64 + j] = d;
    }
    {   // frag build (reads LW only)
        int mi = w;
        int col = 32 * (mi & 1) + 8 * (rr >> 2) + 4 * (mi >> 1) + (rr & 3);
        int base = (8 * g) * 64 + col;
        U8 v;
        v.u[0] = cvtpk(LW[base],       LW[base + 64]);
        v.u[1] = cvtpk(LW[base + 128], LW[base + 192]);
        v.u[2] = cvtpk(LW[base + 256], LW[base + 320]);
        v.u[3] = cvtpk(LW[base + 384], LW[base + 448]);
        ((short8*)(ws + OFF_W1F))[((size_t)f * 4 + mi) * 64 + lane] = v.s8;
    }
    __syncthreads();
    if (t < 64) {
        float d = red[t] + red[64 + t] + red[128 + t] + red[192 + t];
        int dst = 32 * ((t >> 2) & 1) + 16 * (t >> 5) + 4 * ((t >> 3) & 3) + (t & 3);
        tab[64 + dst] = -d;
    }
    __syncthreads();

    // ---- phase 2: W2 -> -d2, w2 frag image ----
    *(float4*)&LW[t * 4]        = *(const float4*)&W2f[t * 4];
    *(float4*)&LW[1024 + t * 4] = *(const float4*)&W2f[1024 + t * 4];
    __syncthreads();
    {
        int o = t & 31, hc = t >> 5;
        float d = 0.f;
#pragma unroll
        for (int k = 0; k < 8; ++k) {
            int h = hc * 8 + k;
            d += b2[f * 64 + h] * LW[h * 32 + o];
        }
        red[hc * 32 + o] = d;
    }
    {   // frag build
        int m2 = w >> 1, kc = w & 1;
        int base = (32 * kc + 8 * g) * 32 + 16 * m2 + rr;
        U8 v;
        v.u[0] = cvtpk(LW[base],       LW[base + 32]);
        v.u[1] = cvtpk(LW[base + 64],  LW[base + 96]);
        v.u[2] = cvtpk(LW[base + 128], LW[base + 160]);
        v.u[3] = cvtpk(LW[base + 192], LW[base + 224]);
        ((short8*)(ws + OFF_W2F))[((size_t)f * 4 + m2 * 2 + kc) * 64 + lane] = v.s8;
    }
    __syncthreads();
    if (t < 32) {
        float d = 0.f;
#pragma unroll
        for (int k = 0; k < 8; ++k) d += red[k * 32 + t];
        tab[128 + t] = -d;
    }
}

// ---------- tile body: one 16-row tile through both MFMA layers ----------
__device__ __forceinline__ void tile_compute(
    float xv, const short8* w1f, const short8 (&w2f)[2][2],
    const f32x4& A0, const f32x4& A1, const f32x4& C0, const f32x4& C1,
    const f32x4* nd1, const f32x4* nd2, f32x4& c0, f32x4& c1)
{
    union U8 { uint32 u[4]; short8 s8; };
    U8 hb;
    hb.u[0] = cvtpk(clip01(fmaf(xv, A0[0], C0[0])), clip01(fmaf(xv, A0[1], C0[1])));
    hb.u[1] = cvtpk(clip01(fmaf(xv, A0[2], C0[2])), clip01(fmaf(xv, A0[3], C0[3])));
    hb.u[2] = cvtpk(clip01(fmaf(xv, A1[0], C1[0])), clip01(fmaf(xv, A1[1], C1[1])));
    hb.u[3] = cvtpk(clip01(fmaf(xv, A1[2], C1[2])), clip01(fmaf(xv, A1[3], C1[3])));
    short8 b0f = hb.s8;

    f32x4 a0 = __builtin_amdgcn_mfma_f32_16x16x32_bf16(w1f[0], b0f, nd1[0], 0, 0, 0);
    f32x4 a1 = __builtin_amdgcn_mfma_f32_16x16x32_bf16(w1f[1], b0f, nd1[1], 0, 0, 0);
    f32x4 a2 = __builtin_amdgcn_mfma_f32_16x16x32_bf16(w1f[2], b0f, nd1[2], 0, 0, 0);
    f32x4 a3 = __builtin_amdgcn_mfma_f32_16x16x32_bf16(w1f[3], b0f, nd1[3], 0, 0, 0);

    U8 r0, r1;
    r0.u[0] = cvtpk(fmaxf(a0[0], 0.f), fmaxf(a0[1], 0.f));
    r0.u[1] = cvtpk(fmaxf(a0[2], 0.f), fmaxf(a0[3], 0.f));
    r0.u[2] = cvtpk(fmaxf(a2[0], 0.f), fmaxf(a2[1], 0.f));
    r0.u[3] = cvtpk(fmaxf(a2[2], 0.f), fmaxf(a2[3], 0.f));
    r1.u[0] = cvtpk(fmaxf(a1[0], 0.f), fmaxf(a1[1], 0.f));
    r1.u[1] = cvtpk(fmaxf(a1[2], 0.f), fmaxf(a1[3], 0.f));
    r1.u[2] = cvtpk(fmaxf(a3[0], 0.f), fmaxf(a3[1], 0.f));
    r1.u[3] = cvtpk(fmaxf(a3[2], 0.f), fmaxf(a3[3], 0.f));

    c0 = __builtin_amdgcn_mfma_f32_16x16x32_bf16(w2f[0][0], r0.s8, nd2[0], 0, 0, 0);
    c0 = __builtin_amdgcn_mfma_f32_16x16x32_bf16(w2f[0][1], r1.s8, c0, 0, 0, 0);
    c1 = __builtin_amdgcn_mfma_f32_16x16x32_bf16(w2f[1][0], r0.s8, nd2[1], 0, 0, 0);
    c1 = __builtin_amdgcn_mfma_f32_16x16x32_bf16(w2f[1][1], r1.s8, c1, 0, 0, 0);
}

// ---------- K1: main — 4 features x 1024 rows per block, 2-chain, relaxed VGPR cap ----------
// launch_bounds(256, 2): cap 256 VGPR so fragments + MFMA accumulators stay in arch
// VGPRs (no AGPR split -> no v_accvgpr_read/write shuttle tax on the VALU pipe).
// grid (4,128) = 512 blocks = exactly 2 blocks/CU resident — no tail rounds.
__global__ __launch_bounds__(256, 2) void nam_main(
    const float* __restrict__ x, const float* __restrict__ Wl,
    const char* __restrict__ ws, float* __restrict__ fout, float* __restrict__ part)
{
    const int fq = blockIdx.y;              // 0..127
    const int f0 = fq * FPB;
    const int rbase = blockIdx.x * RB;
    const int t = threadIdx.x;
    const int w = t >> 6, lane = t & 63;
    const int g = lane >> 4, rr = lane & 15;
    const int f = f0 + w;

    __shared__ float sx[FPB * RB];          // [fi][1024] 16 KB
    __shared__ float sfo[FPB * RB];         // [fi][1024] 16 KB

    // stage x (natural layout): 16 floats per thread, 4 features per float4
#pragma unroll
    for (int kk = 0; kk < 4; ++kk) {
        int r = t + 256 * kk;
        float4 v = *(const float4*)(x + (size_t)(rbase + r) * F + f0);
        sx[0 * RB + r] = v.x; sx[1 * RB + r] = v.y;
        sx[2 * RB + r] = v.z; sx[3 * RB + r] = v.w;
    }

    // per-wave weight fragments + tables (all aligned vector loads from L2)
    const short8* w1img = (const short8*)(ws + OFF_W1F);
    const short8* w2img = (const short8*)(ws + OFF_W2F);
    short8 w1f[4], w2f[2][2];
#pragma unroll
    for (int mi = 0; mi < 4; ++mi) w1f[mi] = w1img[((size_t)f * 4 + mi) * 64 + lane];
#pragma unroll
    for (int m2 = 0; m2 < 2; ++m2)
#pragma unroll
        for (int kc = 0; kc < 2; ++kc)
            w2f[m2][kc] = w2img[((size_t)f * 4 + m2 * 2 + kc) * 64 + lane];

    const f32x4* tabv = (const f32x4*)((const float*)(ws + OFF_TAB) + (size_t)f * 160);
    f32x4 A0 = tabv[2 * g], A1 = tabv[2 * g + 1];
    f32x4 C0 = tabv[8 + 2 * g], C1 = tabv[8 + 2 * g + 1];
    f32x4 nd1[4];
#pragma unroll
    for (int mi = 0; mi < 4; ++mi) nd1[mi] = tabv[16 + 4 * mi + g];
    f32x4 nd2[2];
#pragma unroll
    for (int m2 = 0; m2 < 2; ++m2) nd2[m2] = tabv[32 + 4 * m2 + g];
    f32x4 wl0 = *(const f32x4*)(Wl + f * 32 + 4 * g);
    f32x4 wl1 = *(const f32x4*)(Wl + f * 32 + 16 + 4 * g);

    __syncthreads();

    const float* sxf = sx + w * RB;
    float* sfof = sfo + w * RB;

    // 64 tiles as 32 independent pairs (2 chains in flight per wave)
    for (int k = 0; k < 32; ++k) {
        float xv0 = sxf[32 * k + rr];
        float xv1 = sxf[32 * k + 16 + rr];
        f32x4 c00, c01, c10, c11;
        tile_compute(xv0, w1f, w2f, A0, A1, C0, C1, nd1, nd2, c00, c01);
        tile_compute(xv1, w1f, w2f, A0, A1, C0, C1, nd1, nd2, c10, c11);

        float p0 = 0.f, p1 = 0.f;
#pragma unroll
        for (int r = 0; r < 4; ++r) {
            p0 = fmaf(fmaxf(c00[r], 0.f), wl0[r], p0);
            p0 = fmaf(fmaxf(c01[r], 0.f), wl1[r], p0);
            p1 = fmaf(fmaxf(c10[r], 0.f), wl0[r], p1);
            p1 = fmaf(fmaxf(c11[r], 0.f), wl1[r], p1);
        }
        p0 += __shfl_xor(p0, 16, 64);
        p0 += __shfl_xor(p0, 32, 64);
        p1 += __shfl_xor(p1, 16, 64);
        p1 += __shfl_xor(p1, 32, 64);
        if (lane < 16) {
            sfof[32 * k + lane] = p0;
            sfof[32 * k + 16 + lane] = p1;
        }
    }

    __syncthreads();

    // coalesced-LDS -> global fout (natural layout) + per-(fq,row) partial sums
#pragma unroll
    for (int kk = 0; kk < 4; ++kk) {
        int r = t + 256 * kk;
        float v0 = sfo[0 * RB + r], v1 = sfo[1 * RB + r];
        float v2 = sfo[2 * RB + r], v3 = sfo[3 * RB + r];
        *(float4*)(fout + (size_t)(rbase + r) * F + f0) = make_float4(v0, v1, v2, v3);
        part[(size_t)fq * NB + rbase + r] = (v0 + v1) + (v2 + v3);
    }
}

// ---------- K2: out0[r] = bias + sum of 128 partials ----------
__global__ __launch_bounds__(256) void nam_sum(const float* __restrict__ part,
                                               const float* __restrict__ ob,
                                               float* __restrict__ out0) {
    int r = blockIdx.x * 256 + threadIdx.x;
    float s = ob[0];
#pragma unroll 8
    for (int q = 0; q < NFQ; ++q) s += part[(size_t)q * NB + r];
    out0[r] = s;
}

// ================= fallback (round-1 VALU kernel, used if ws too small) =================
namespace fbk { constexpr int S = 32, H1 = 64, H2 = 32, BLK = 256, ROWS = 2, P1 = 36; }
__global__ __launch_bounds__(256, 2) void fb_main(
    const float* __restrict__ x,  const float* __restrict__ W0,
    const float* __restrict__ b0, const float* __restrict__ W1,
    const float* __restrict__ b1, const float* __restrict__ W2,
    const float* __restrict__ b2, const float* __restrict__ Wl,
    float* __restrict__ fout) {
    using namespace fbk;
    const int f = blockIdx.y;
    const int bbase = blockIdx.x * (BLK * ROWS);
    const int t = threadIdx.x;
    __shared__ float W0e[S * S];
    __shared__ float W1t[H1 * P1];
    __shared__ float W2l[H1 * H2];
    __shared__ float sb0[S], sb1[S], sb2[H1];
    __shared__ float sA[S], sC[S], sd1[H1], sd2[H2], sWl[H2];
    {
        float4 wv = *reinterpret_cast<const float4*>(W0 + (size_t)f * S * S + t * 4);
        W0e[t * 4 + 0] = expf(wv.x); W0e[t * 4 + 1] = expf(wv.y);
        W0e[t * 4 + 2] = expf(wv.z); W0e[t * 4 + 3] = expf(wv.w);
    }
    if (t < S) sb0[t] = b0[f * S + t];
    else if (t < 2 * S) sb1[t - S] = b1[f * S + (t - S)];
    else if (t < 2 * S + H1) sb2[t - 2 * S] = b2[f * H1 + (t - 2 * S)];
    else if (t < 2 * S + H1 + H2) sWl[t - 2 * S - H1] = Wl[f * H2 + (t - 2 * S - H1)];
#pragma unroll
    for (int k = 0; k < (S * H1) / BLK; ++k) {
        int i = t + BLK * k; int s = i >> 6, j = i & 63;
        W1t[j * P1 + s] = W1[(size_t)f * S * H1 + i];
    }
#pragma unroll
    for (int k = 0; k < (H1 * H2) / BLK; ++k) {
        int i = t + BLK * k; W2l[i] = W2[(size_t)f * H1 * H2 + i];
    }
    __syncthreads();
    if (t < S) {
        int j = t; float a = 0.f, c = 0.f;
#pragma unroll
        for (int s = 0; s < S; ++s) { float e = W0e[s * S + j]; a += e; c += sb0[s] * e; }
        sA[j] = a; sC[j] = c;
    } else if (t >= 64 && t < 64 + H1) {
        int j = t - 64; float d = 0.f;
#pragma unroll
        for (int s = 0; s < S; ++s) d += sb1[s] * W1t[j * P1 + s];
        sd1[j] = d;
    } else if (t >= 128 && t < 128 + H2) {
        int o = t - 128; float d = 0.f;
#pragma unroll
        for (int h = 0; h < H1; ++h) d += sb2[h] * W2l[h * H2 + o];
        sd2[o] = d;
    }
    __syncthreads();
    const int ra = bbase + t, rb = bbase + BLK + t;
    const float xa = x[(size_t)ra * F + f], xb = x[(size_t)rb * F + f];
    float h0a[S], h0b[S];
#pragma unroll
    for (int j = 0; j < S; ++j) {
        float A = sA[j], C = sC[j];
        h0a[j] = fminf(fmaxf(fmaf(xa, A, -C), 0.f), 1.f);
        h0b[j] = fminf(fmaxf(fmaf(xb, A, -C), 0.f), 1.f);
    }
    float acc2a[H2], acc2b[H2];
#pragma unroll
    for (int o = 0; o < H2; ++o) { float d = sd2[o]; acc2a[o] = -d; acc2b[o] = -d; }
#pragma unroll 2
    for (int j = 0; j < H1; ++j) {
        float wr[S];
#pragma unroll
        for (int q = 0; q < S / 4; ++q)
            *reinterpret_cast<float4*>(&wr[4 * q]) = reinterpret_cast<const float4*>(&W1t[j * P1])[q];
        float d1j = sd1[j];
        float pa0 = -d1j, pa1 = 0.f, pb0 = -d1j, pb1 = 0.f;
#pragma unroll
        for (int s = 0; s < S; s += 2) {
            pa0 = fmaf(h0a[s], wr[s], pa0); pb0 = fmaf(h0b[s], wr[s], pb0);
            pa1 = fmaf(h0a[s + 1], wr[s + 1], pa1); pb1 = fmaf(h0b[s + 1], wr[s + 1], pb1);
        }
        float h1a = fmaxf(pa0 + pa1, 0.f), h1b = fmaxf(pb0 + pb1, 0.f);
        float w2r[H2];
#pragma unroll
        for (int q = 0; q < H2 / 4; ++q)
            *reinterpret_cast<float4*>(&w2r[4 * q]) = reinterpret_cast<const float4*>(&W2l[j * H2])[q];
#pragma unroll
        for (int o = 0; o < H2; ++o) {
            acc2a[o] = fmaf(h1a, w2r[o], acc2a[o]); acc2b[o] = fmaf(h1b, w2r[o], acc2b[o]);
        }
    }
    float outa = 0.f, outb = 0.f;
#pragma unroll
    for (int o = 0; o < H2; ++o) {
        outa = fmaf(fmaxf(acc2a[o], 0.f), sWl[o], outa);
        outb = fmaf(fmaxf(acc2b[o], 0.f), sWl[o], outb);
    }
    fout[(size_t)ra * F + f] = outa;
    fout[(size_t)rb * F + f] = outb;
}
__global__ __launch_bounds__(256) void fb_rowsum(
    const float* __restrict__ fout, const float* __restrict__ out_bias,
    float* __restrict__ out0) {
    const int wave = threadIdx.x >> 6, lane = threadIdx.x & 63;
    const int b = blockIdx.x * 4 + wave;
    float s = 0.f;
#pragma unroll
    for (int k = 0; k < F / 64; ++k) s += fout[(size_t)b * F + k * 64 + lane];
#pragma unroll
    for (int off = 32; off; off >>= 1) s += __shfl_down(s, off, 64);
    if (lane == 0) out0[b] = s + out_bias[0];
}

extern "C" void kernel_launch(void* const* d_in, const int* in_sizes, int n_in,
                              void* d_out, int out_size, void* d_ws, size_t ws_size,
                              hipStream_t stream) {
    const float* x  = (const float*)d_in[0];
    const float* W0 = (const float*)d_in[1];
    const float* b0 = (const float*)d_in[2];
    const float* W1 = (const float*)d_in[3];
    const float* b1 = (const float*)d_in[4];
    const float* W2 = (const float*)d_in[5];
    const float* b2 = (const float*)d_in[6];
    const float* Wl = (const float*)d_in[7];
    const float* ob = (const float*)d_in[8];

    float* out0 = (float*)d_out;      // (B,)
    float* fout = out0 + NB;          // (B,F)

    if (ws_size >= WS_NEED) {
        char* ws = (char*)d_ws;
        float* part = (float*)(ws + OFF_PART);
        nam_prep<<<F, 256, 0, stream>>>(W0, b0, W1, b1, W2, b2, ws);
        nam_main<<<dim3(NB / RB, NFQ), 256, 0, stream>>>(x, Wl, ws, fout, part);
        nam_sum <<<NB / 256, 256, 0, stream>>>(part, ob, out0);
    } else {
        dim3 grid(NB / (fbk::BLK * fbk::ROWS), F);
        fb_main<<<grid, fbk::BLK, 0, stream>>>(x, W0, b0, W1, b1, W2, b2, Wl, fout);
        fb_rowsum<<<NB / 4, 256, 0, stream>>>(fout, ob, out0);
    }
}

// Round 9
// 48.953 us; speedup vs baseline: 1.1036x; 1.1036x over previous
//
#include <hip/hip_runtime.h>

typedef __attribute__((ext_vector_type(8))) short short8;
typedef __attribute__((ext_vector_type(4))) float f32x4;
typedef unsigned int uint32;

namespace {
constexpr int F = 512, NB = 4096;
constexpr int RB = 512;          // rows per block (and per wave)
constexpr int FPB = 4;           // features per block = waves per block
constexpr int NFQ = F / FPB;     // 128 feature-quads
// workspace layout
constexpr size_t OFF_W1F  = 0;                                   // F*4*64*16B = 2 MB
constexpr size_t OFF_W2F  = OFF_W1F + (size_t)F * 4 * 64 * 16;   // 2 MB
constexpr size_t OFF_TAB  = OFF_W2F + (size_t)F * 4 * 64 * 16;   // F*160*4 = 320 KB
constexpr size_t OFF_PART = OFF_TAB + (size_t)F * 160 * 4;       // NFQ*NB*4 = 2 MB
constexpr size_t WS_NEED  = OFF_PART + (size_t)NFQ * NB * 4;     // ~6.3 MB
}

__device__ __forceinline__ uint32 cvtpk(float lo, float hi) { // packed bf16 pair (RNE)
    uint32 r;
    asm("v_cvt_pk_bf16_f32 %0, %1, %2" : "=v"(r) : "v"(lo), "v"(hi));
    return r;
}
__device__ __forceinline__ float clip01(float v) {
    return __builtin_amdgcn_fmed3f(v, 0.f, 1.f);
}

// All-VGPR inline-asm MFMA (forces fragments+accumulators into arch VGPRs,
// killing the v_accvgpr shuttle the builtin path generated — R6: arch=64).
// HAZARDS ARE OURS: inline asm is invisible to the compiler's hazard
// recognizer, so every MFMA<->VALU boundary in the tile loop is fenced with
// sched_barrier(0) + s_nop (R8 failed absmax=40 without them).
__device__ __forceinline__ f32x4 mfma_init(short8 a, short8 b, f32x4 c) {
    f32x4 d;
    asm("v_mfma_f32_16x16x32_bf16 %0, %1, %2, %3"
        : "=&v"(d) : "v"(a), "v"(b), "v"(c));
    return d;
}
__device__ __forceinline__ void mfma_acc(f32x4& c, short8 a, short8 b) {
    asm("v_mfma_f32_16x16x32_bf16 %0, %1, %2, %0"
        : "+v"(c) : "v"(a), "v"(b));
}
#define SBAR()      __builtin_amdgcn_sched_barrier(0)
#define NOP_VM()    asm volatile("s_nop 1")            // VALU write -> MFMA src read
#define NOP_MV()    asm volatile("s_nop 7\n\ts_nop 7") // MFMA D write -> VALU read

// ---------- K0: prep — per-feature tables (pre-negated/permuted) + bf16 frag images ----------
// pi(j): j=[b5 b4 b3 b2 b1 b0] -> [b4 b3 b2 b5 b1 b0]; W1 A-frag columns pre-permuted so
// layer-1 D-registers are directly layer-2 B-fragments (no LDS transpose in main).
// tab layout per f (160 f32): [0:32) A | [32:64) -C | [64:128) -d1 (pi-permuted) | [128:160) -d2
__global__ __launch_bounds__(256) void nam_prep(
    const float* __restrict__ W0, const float* __restrict__ b0,
    const float* __restrict__ W1, const float* __restrict__ b1,
    const float* __restrict__ W2, const float* __restrict__ b2,
    char* __restrict__ ws)
{
    const int f = blockIdx.x;
    const int t = threadIdx.x;
    const int lane = t & 63, w = t >> 6, g = lane >> 4, rr = lane & 15;

    __shared__ float LW[2048];
    __shared__ float red[256], red2[256];

    const float* W0f = W0 + (size_t)f * 1024;
    const float* W1f = W1 + (size_t)f * 2048;
    const float* W2f = W2 + (size_t)f * 2048;
    float* tab = (float*)(ws + OFF_TAB) + (size_t)f * 160;
    union U8 { uint32 u[4]; short8 s8; };

    // ---- phase 0: W0 -> A, -C ----
    *(float4*)&LW[t * 4] = *(const float4*)&W0f[t * 4];
    __syncthreads();
    {
        int j = t & 31, sc = t >> 5;
        float a = 0.f, c = 0.f;
#pragma unroll
        for (int k = 0; k < 4; ++k) {
            int s = sc * 4 + k;
            float e = expf(LW[s * 32 + j]);
            a += e; c += b0[f * 32 + s] * e;
        }
        red[sc * 32 + j] = a; red2[sc * 32 + j] = c;
    }
    __syncthreads();
    if (t < 32) {
        float a = 0.f, c = 0.f;
#pragma unroll
        for (int k = 0; k < 8; ++k) { a += red[k * 32 + t]; c += red2[k * 32 + t]; }
        tab[t] = a; tab[32 + t] = -c;
    }
    __syncthreads();

    // ---- phase 1: W1 -> -d1 (permuted), w1 frag image ----
    *(float4*)&LW[t * 4]        = *(const float4*)&W1f[t * 4];
    *(float4*)&LW[1024 + t * 4] = *(const float4*)&W1f[1024 + t * 4];
    __syncthreads();
    {
        int j = t & 63, sc = t >> 6;
        float d = 0.f;
#pragma unroll
        for (int k = 0; k < 8; ++k) {
            int s = sc * 8 + k;
            d += b1[f * 32 + s] * LW[s * 64 + j];
        }
        red[sc * 64 + j] = d;
    }
    {   // frag build (reads LW only)
        int mi = w;
        int col = 32 * (mi & 1) + 8 * (rr >> 2) + 4 * (mi >> 1) + (rr & 3);
        int base = (8 * g) * 64 + col;
        U8 v;
        v.u[0] = cvtpk(LW[base],       LW[base + 64]);
        v.u[1] = cvtpk(LW[base + 128], LW[base + 192]);
        v.u[2] = cvtpk(LW[base + 256], LW[base + 320]);
        v.u[3] = cvtpk(LW[base + 384], LW[base + 448]);
        ((short8*)(ws + OFF_W1F))[((size_t)f * 4 + mi) * 64 + lane] = v.s8;
    }
    __syncthreads();
    if (t < 64) {
        float d = red[t] + red[64 + t] + red[128 + t] + red[192 + t];
        int dst = 32 * ((t >> 2) & 1) + 16 * (t >> 5) + 4 * ((t >> 3) & 3) + (t & 3);
        tab[64 + dst] = -d;
    }
    __syncthreads();

    // ---- phase 2: W2 -> -d2, w2 frag image ----
    *(float4*)&LW[t * 4]        = *(const float4*)&W2f[t * 4];
    *(float4*)&LW[1024 + t * 4] = *(const float4*)&W2f[1024 + t * 4];
    __syncthreads();
    {
        int o = t & 31, hc = t >> 5;
        float d = 0.f;
#pragma unroll
        for (int k = 0; k < 8; ++k) {
            int h = hc * 8 + k;
            d += b2[f * 64 + h] * LW[h * 32 + o];
        }
        red[hc * 32 + o] = d;
    }
    {   // frag build
        int m2 = w >> 1, kc = w & 1;
        int base = (32 * kc + 8 * g) * 32 + 16 * m2 + rr;
        U8 v;
        v.u[0] = cvtpk(LW[base],       LW[base + 32]);
        v.u[1] = cvtpk(LW[base + 64],  LW[base + 96]);
        v.u[2] = cvtpk(LW[base + 128], LW[base + 160]);
        v.u[3] = cvtpk(LW[base + 192], LW[base + 224]);
        ((short8*)(ws + OFF_W2F))[((size_t)f * 4 + m2 * 2 + kc) * 64 + lane] = v.s8;
    }
    __syncthreads();
    if (t < 32) {
        float d = 0.f;
#pragma unroll
        for (int k = 0; k < 8; ++k) d += red[k * 32 + t];
        tab[128 + t] = -d;
    }
}

__device__ __forceinline__ short8 make_hb(float xv, const f32x4& A0, const f32x4& A1,
                                          const f32x4& C0, const f32x4& C1) {
    union { uint32 u[4]; short8 s8; } hb;
    hb.u[0] = cvtpk(clip01(fmaf(xv, A0[0], C0[0])), clip01(fmaf(xv, A0[1], C0[1])));
    hb.u[1] = cvtpk(clip01(fmaf(xv, A0[2], C0[2])), clip01(fmaf(xv, A0[3], C0[3])));
    hb.u[2] = cvtpk(clip01(fmaf(xv, A1[0], C1[0])), clip01(fmaf(xv, A1[1], C1[1])));
    hb.u[3] = cvtpk(clip01(fmaf(xv, A1[2], C1[2])), clip01(fmaf(xv, A1[3], C1[3])));
    return hb.s8;
}
__device__ __forceinline__ short8 packrelu(const f32x4& x, const f32x4& y) {
    union { uint32 u[4]; short8 s8; } r;
    r.u[0] = cvtpk(fmaxf(x[0], 0.f), fmaxf(x[1], 0.f));
    r.u[1] = cvtpk(fmaxf(x[2], 0.f), fmaxf(x[3], 0.f));
    r.u[2] = cvtpk(fmaxf(y[0], 0.f), fmaxf(y[1], 0.f));
    r.u[3] = cvtpk(fmaxf(y[2], 0.f), fmaxf(y[3], 0.f));
    return r.s8;
}

// ---------- K1: main — 4 features x 512 rows per block, 2-chain, all-VGPR MFMA ----------
__global__ __launch_bounds__(256, 2) void nam_main(
    const float* __restrict__ x, const float* __restrict__ Wl,
    const char* __restrict__ ws, float* __restrict__ fout, float* __restrict__ part)
{
    const int fq = blockIdx.y;              // 0..127
    const int f0 = fq * FPB;
    const int rbase = blockIdx.x * RB;
    const int t = threadIdx.x;
    const int w = t >> 6, lane = t & 63;
    const int g = lane >> 4, rr = lane & 15;
    const int f = f0 + w;

    __shared__ float sx[FPB * RB];          // [fi][512] 8 KB
    __shared__ float sfo[FPB * RB];         // [fi][512] 8 KB

    // stage x (natural layout): 8 floats per thread, 4 features per float4
#pragma unroll
    for (int kk = 0; kk < 2; ++kk) {
        int r = t + 256 * kk;
        float4 v = *(const float4*)(x + (size_t)(rbase + r) * F + f0);
        sx[0 * RB + r] = v.x; sx[1 * RB + r] = v.y;
        sx[2 * RB + r] = v.z; sx[3 * RB + r] = v.w;
    }

    // per-wave weight fragments + tables (all aligned vector loads from L2)
    const short8* w1img = (const short8*)(ws + OFF_W1F);
    const short8* w2img = (const short8*)(ws + OFF_W2F);
    short8 w1f[4], w2f[2][2];
#pragma unroll
    for (int mi = 0; mi < 4; ++mi) w1f[mi] = w1img[((size_t)f * 4 + mi) * 64 + lane];
#pragma unroll
    for (int m2 = 0; m2 < 2; ++m2)
#pragma unroll
        for (int kc = 0; kc < 2; ++kc)
            w2f[m2][kc] = w2img[((size_t)f * 4 + m2 * 2 + kc) * 64 + lane];

    const f32x4* tabv = (const f32x4*)((const float*)(ws + OFF_TAB) + (size_t)f * 160);
    f32x4 A0 = tabv[2 * g], A1 = tabv[2 * g + 1];
    f32x4 C0 = tabv[8 + 2 * g], C1 = tabv[8 + 2 * g + 1];
    f32x4 nd1[4];
#pragma unroll
    for (int mi = 0; mi < 4; ++mi) nd1[mi] = tabv[16 + 4 * mi + g];
    f32x4 nd2[2];
#pragma unroll
    for (int m2 = 0; m2 < 2; ++m2) nd2[m2] = tabv[32 + 4 * m2 + g];
    f32x4 wl0 = *(const f32x4*)(Wl + f * 32 + 4 * g);
    f32x4 wl1 = *(const f32x4*)(Wl + f * 32 + 16 + 4 * g);

    __syncthreads();

    const float* sxf = sx + w * RB;
    float* sfof = sfo + w * RB;

    for (int k = 0; k < 16; ++k) {
        float xv0 = sxf[32 * k + rr];
        float xv1 = sxf[32 * k + 16 + rr];

        short8 hb0 = make_hb(xv0, A0, A1, C0, C1);
        short8 hb1 = make_hb(xv1, A0, A1, C0, C1);

        SBAR(); NOP_VM();                       // VALU(hb) -> MFMA src gap
        // layer 1: 8 MFMAs, both chains
        f32x4 a00 = mfma_init(w1f[0], hb0, nd1[0]);
        f32x4 a01 = mfma_init(w1f[1], hb0, nd1[1]);
        f32x4 a02 = mfma_init(w1f[2], hb0, nd1[2]);
        f32x4 a03 = mfma_init(w1f[3], hb0, nd1[3]);
        f32x4 a10 = mfma_init(w1f[0], hb1, nd1[0]);
        f32x4 a11 = mfma_init(w1f[1], hb1, nd1[1]);
        f32x4 a12 = mfma_init(w1f[2], hb1, nd1[2]);
        f32x4 a13 = mfma_init(w1f[3], hb1, nd1[3]);
        SBAR(); NOP_MV();                       // MFMA D -> VALU read gap

        // relu + pack: registers ARE the layer-2 B-frags
        short8 r00 = packrelu(a00, a02);
        short8 r01 = packrelu(a01, a03);
        short8 r10 = packrelu(a10, a12);
        short8 r11 = packrelu(a11, a13);

        SBAR(); NOP_VM();                       // VALU(r) -> MFMA src gap
        // layer 2: 8 MFMAs; inits first, dependent accumulates trail by 4
        f32x4 c00 = mfma_init(w2f[0][0], r00, nd2[0]);
        f32x4 c01 = mfma_init(w2f[1][0], r00, nd2[1]);
        f32x4 c10 = mfma_init(w2f[0][0], r10, nd2[0]);
        f32x4 c11 = mfma_init(w2f[1][0], r10, nd2[1]);
        mfma_acc(c00, w2f[0][1], r01);
        mfma_acc(c01, w2f[1][1], r01);
        mfma_acc(c10, w2f[0][1], r11);
        mfma_acc(c11, w2f[1][1], r11);
        SBAR(); NOP_MV();                       // MFMA D -> VALU read gap

        // epilogue
        float p0 = 0.f, p1 = 0.f;
#pragma unroll
        for (int r = 0; r < 4; ++r) {
            p0 = fmaf(fmaxf(c00[r], 0.f), wl0[r], p0);
            p0 = fmaf(fmaxf(c01[r], 0.f), wl1[r], p0);
            p1 = fmaf(fmaxf(c10[r], 0.f), wl0[r], p1);
            p1 = fmaf(fmaxf(c11[r], 0.f), wl1[r], p1);
        }
        p0 += __shfl_xor(p0, 16, 64);
        p0 += __shfl_xor(p0, 32, 64);
        p1 += __shfl_xor(p1, 16, 64);
        p1 += __shfl_xor(p1, 32, 64);
        if (lane < 16) {
            sfof[32 * k + lane] = p0;
            sfof[32 * k + 16 + lane] = p1;
        }
    }

    __syncthreads();

    // coalesced-LDS -> global fout (natural layout) + per-(fq,row) partial sums
#pragma unroll
    for (int kk = 0; kk < 2; ++kk) {
        int r = t + 256 * kk;
        float v0 = sfo[0 * RB + r], v1 = sfo[1 * RB + r];
        float v2 = sfo[2 * RB + r], v3 = sfo[3 * RB + r];
        *(float4*)(fout + (size_t)(rbase + r) * F + f0) = make_float4(v0, v1, v2, v3);
        part[(size_t)fq * NB + rbase + r] = (v0 + v1) + (v2 + v3);
    }
}

// ---------- K2: out0[r] = bias + sum of 128 partials ----------
__global__ __launch_bounds__(256) void nam_sum(const float* __restrict__ part,
                                               const float* __restrict__ ob,
                                               float* __restrict__ out0) {
    int r = blockIdx.x * 256 + threadIdx.x;
    float s = ob[0];
#pragma unroll 8
    for (int q = 0; q < NFQ; ++q) s += part[(size_t)q * NB + r];
    out0[r] = s;
}

// ================= fallback (round-1 VALU kernel, used if ws too small) =================
namespace fbk { constexpr int S = 32, H1 = 64, H2 = 32, BLK = 256, ROWS = 2, P1 = 36; }
__global__ __launch_bounds__(256, 2) void fb_main(
    const float* __restrict__ x,  const float* __restrict__ W0,
    const float* __restrict__ b0, const float* __restrict__ W1,
    const float* __restrict__ b1, const float* __restrict__ W2,
    const float* __restrict__ b2, const float* __restrict__ Wl,
    float* __restrict__ fout) {
    using namespace fbk;
    const int f = blockIdx.y;
    const int bbase = blockIdx.x * (BLK * ROWS);
    const int t = threadIdx.x;
    __shared__ float W0e[S * S];
    __shared__ float W1t[H1 * P1];
    __shared__ float W2l[H1 * H2];
    __shared__ float sb0[S], sb1[S], sb2[H1];
    __shared__ float sA[S], sC[S], sd1[H1], sd2[H2], sWl[H2];
    {
        float4 wv = *reinterpret_cast<const float4*>(W0 + (size_t)f * S * S + t * 4);
        W0e[t * 4 + 0] = expf(wv.x); W0e[t * 4 + 1] = expf(wv.y);
        W0e[t * 4 + 2] = expf(wv.z); W0e[t * 4 + 3] = expf(wv.w);
    }
    if (t < S) sb0[t] = b0[f * S + t];
    else if (t < 2 * S) sb1[t - S] = b1[f * S + (t - S)];
    else if (t < 2 * S + H1) sb2[t - 2 * S] = b2[f * H1 + (t - 2 * S)];
    else if (t < 2 * S + H1 + H2) sWl[t - 2 * S - H1] = Wl[f * H2 + (t - 2 * S - H1)];
#pragma unroll
    for (int k = 0; k < (S * H1) / BLK; ++k) {
        int i = t + BLK * k; int s = i >> 6, j = i & 63;
        W1t[j * P1 + s] = W1[(size_t)f * S * H1 + i];
    }
#pragma unroll
    for (int k = 0; k < (H1 * H2) / BLK; ++k) {
        int i = t + BLK * k; W2l[i] = W2[(size_t)f * H1 * H2 + i];
    }
    __syncthreads();
    if (t < S) {
        int j = t; float a = 0.f, c = 0.f;
#pragma unroll
        for (int s = 0; s < S; ++s) { float e = W0e[s * S + j]; a += e; c += sb0[s] * e; }
        sA[j] = a; sC[j] = c;
    } else if (t >= 64 && t < 64 + H1) {
        int j = t - 64; float d = 0.f;
#pragma unroll
        for (int s = 0; s < S; ++s) d += sb1[s] * W1t[j * P1 + s];
        sd1[j] = d;
    } else if (t >= 128 && t < 128 + H2) {
        int o = t - 128; float d = 0.f;
#pragma unroll
        for (int h = 0; h < H1; ++h) d += sb2[h] * W2l[h * H2 + o];
        sd2[o] = d;
    }
    __syncthreads();
    const int ra = bbase + t, rb = bbase + BLK + t;
    const float xa = x[(size_t)ra * F + f], xb = x[(size_t)rb * F + f];
    float h0a[S], h0b[S];
#pragma unroll
    for (int j = 0; j < S; ++j) {
        float A = sA[j], C = sC[j];
        h0a[j] = fminf(fmaxf(fmaf(xa, A, -C), 0.f), 1.f);
        h0b[j] = fminf(fmaxf(fmaf(xb, A, -C), 0.f), 1.f);
    }
    float acc2a[H2], acc2b[H2];
#pragma unroll
    for (int o = 0; o < H2; ++o) { float d = sd2[o]; acc2a[o] = -d; acc2b[o] = -d; }
#pragma unroll 2
    for (int j = 0; j < H1; ++j) {
        float wr[S];
#pragma unroll
        for (int q = 0; q < S / 4; ++q)
            *reinterpret_cast<float4*>(&wr[4 * q]) = reinterpret_cast<const float4*>(&W1t[j * P1])[q];
        float d1j = sd1[j];
        float pa0 = -d1j, pa1 = 0.f, pb0 = -d1j, pb1 = 0.f;
#pragma unroll
        for (int s = 0; s < S; s += 2) {
            pa0 = fmaf(h0a[s], wr[s], pa0); pb0 = fmaf(h0b[s], wr[s], pb0);
            pa1 = fmaf(h0a[s + 1], wr[s + 1], pa1); pb1 = fmaf(h0b[s + 1], wr[s + 1], pb1);
        }
        float h1a = fmaxf(pa0 + pa1, 0.f), h1b = fmaxf(pb0 + pb1, 0.f);
        float w2r[H2];
#pragma unroll
        for (int q = 0; q < H2 / 4; ++q)
            *reinterpret_cast<float4*>(&w2r[4 * q]) = reinterpret_cast<const float4*>(&W2l[j * H2])[q];
#pragma unroll
        for (int o = 0; o < H2; ++o) {
            acc2a[o] = fmaf(h1a, w2r[o], acc2a[o]); acc2b[o] = fmaf(h1b, w2r[o], acc2b[o]);
        }
    }
    float outa = 0.f, outb = 0.f;
#pragma unroll
    for (int o = 0; o < H2; ++o) {
        outa = fmaf(fmaxf(acc2a[o], 0.f), sWl[o], outa);
        outb = fmaf(fmaxf(acc2b[o], 0.f), sWl[o], outb);
    }
    fout[(size_t)ra * F + f] = outa;
    fout[(size_t)rb * F + f] = outb;
}
__global__ __launch_bounds__(256) void fb_rowsum(
    const float* __restrict__ fout, const float* __restrict__ out_bias,
    float* __restrict__ out0) {
    const int wave = threadIdx.x >> 6, lane = threadIdx.x & 63;
    const int b = blockIdx.x * 4 + wave;
    float s = 0.f;
#pragma unroll
    for (int k = 0; k < F / 64; ++k) s += fout[(size_t)b * F + k * 64 + lane];
#pragma unroll
    for (int off = 32; off; off >>= 1) s += __shfl_down(s, off, 64);
    if (lane == 0) out0[b] = s + out_bias[0];
}

extern "C" void kernel_launch(void* const* d_in, const int* in_sizes, int n_in,
                              void* d_out, int out_size, void* d_ws, size_t ws_size,
                              hipStream_t stream) {
    const float* x  = (const float*)d_in[0];
    const float* W0 = (const float*)d_in[1];
    const float* b0 = (const float*)d_in[2];
    const float* W1 = (const float*)d_in[3];
    const float* b1 = (const float*)d_in[4];
    const float* W2 = (const float*)d_in[5];
    const float* b2 = (const float*)d_in[6];
    const float* Wl = (const float*)d_in[7];
    const float* ob = (const float*)d_in[8];

    float* out0 = (float*)d_out;      // (B,)
    float* fout = out0 + NB;          // (B,F)

    if (ws_size >= WS_NEED) {
        char* ws = (char*)d_ws;
        float* part = (float*)(ws + OFF_PART);
        nam_prep<<<F, 256, 0, stream>>>(W0, b0, W1, b1, W2, b2, ws);
        nam_main<<<dim3(NB / RB, NFQ), 256, 0, stream>>>(x, Wl, ws, fout, part);
        nam_sum <<<NB / 256, 256, 0, stream>>>(part, ob, out0);
    } else {
        dim3 grid(NB / (fbk::BLK * fbk::ROWS), F);
        fb_main<<<grid, fbk::BLK, 0, stream>>>(x, W0, b0, W1, b1, W2, b2, Wl, fout);
        fb_rowsum<<<NB / 4, 256, 0, stream>>>(fout, ob, out0);
    }
}

// Round 12
// 44.939 us; speedup vs baseline: 1.2022x; 1.0893x over previous
//
#include <hip/hip_runtime.h>

typedef __attribute__((ext_vector_type(8))) short short8;
typedef __attribute__((ext_vector_type(4))) float f32x4;
typedef unsigned int uint32;

namespace {
constexpr int F = 512, NB = 4096;
constexpr int RB = 256;          // rows per block (and per wave)
constexpr int FPB = 4;           // features per block = waves per block
constexpr int NFQ = F / FPB;     // 128 feature-quads
// workspace layout
constexpr size_t OFF_W1F  = 0;                                   // F*4*64*16B = 2 MB
constexpr size_t OFF_W2F  = OFF_W1F + (size_t)F * 4 * 64 * 16;   // 2 MB
constexpr size_t OFF_TAB  = OFF_W2F + (size_t)F * 4 * 64 * 16;   // F*160*4 = 320 KB
constexpr size_t OFF_PART = OFF_TAB + (size_t)F * 160 * 4;       // NFQ*NB*4 = 2 MB
constexpr size_t WS_NEED  = OFF_PART + (size_t)NFQ * NB * 4;     // ~6.3 MB
}

__device__ __forceinline__ uint32 cvtpk(float lo, float hi) { // packed bf16 pair (RNE)
    uint32 r;
    asm("v_cvt_pk_bf16_f32 %0, %1, %2" : "=v"(r) : "v"(lo), "v"(hi));
    return r;
}
__device__ __forceinline__ float clip01(float v) {
    return __builtin_amdgcn_fmed3f(v, 0.f, 1.f);
}

// ---------- K0: prep — per-feature tables (pre-negated/permuted) + bf16 frag images ----------
// pi(j): j=[b5 b4 b3 b2 b1 b0] -> [b4 b3 b2 b5 b1 b0]; W1 A-frag columns pre-permuted so
// layer-1 D-registers are directly layer-2 B-fragments (no LDS transpose in main).
// tab layout per f (160 f32): [0:32) A | [32:64) -C | [64:128) -d1 (pi-permuted) | [128:160) -d2
__global__ __launch_bounds__(256) void nam_prep(
    const float* __restrict__ W0, const float* __restrict__ b0,
    const float* __restrict__ W1, const float* __restrict__ b1,
    const float* __restrict__ W2, const float* __restrict__ b2,
    char* __restrict__ ws)
{
    const int f = blockIdx.x;
    const int t = threadIdx.x;
    const int lane = t & 63, w = t >> 6, g = lane >> 4, rr = lane & 15;

    __shared__ float LW[2048];
    __shared__ float red[256], red2[256];

    const float* W0f = W0 + (size_t)f * 1024;
    const float* W1f = W1 + (size_t)f * 2048;
    const float* W2f = W2 + (size_t)f * 2048;
    float* tab = (float*)(ws + OFF_TAB) + (size_t)f * 160;
    union U8 { uint32 u[4]; short8 s8; };

    // ---- phase 0: W0 -> A, -C ----
    *(float4*)&LW[t * 4] = *(const float4*)&W0f[t * 4];
    __syncthreads();
    {
        int j = t & 31, sc = t >> 5;
        float a = 0.f, c = 0.f;
#pragma unroll
        for (int k = 0; k < 4; ++k) {
            int s = sc * 4 + k;
            float e = expf(LW[s * 32 + j]);
            a += e; c += b0[f * 32 + s] * e;
        }
        red[sc * 32 + j] = a; red2[sc * 32 + j] = c;
    }
    __syncthreads();
    if (t < 32) {
        float a = 0.f, c = 0.f;
#pragma unroll
        for (int k = 0; k < 8; ++k) { a += red[k * 32 + t]; c += red2[k * 32 + t]; }
        tab[t] = a; tab[32 + t] = -c;
    }
    __syncthreads();

    // ---- phase 1: W1 -> -d1 (permuted), w1 frag image ----
    *(float4*)&LW[t * 4]        = *(const float4*)&W1f[t * 4];
    *(float4*)&LW[1024 + t * 4] = *(const float4*)&W1f[1024 + t * 4];
    __syncthreads();
    {
        int j = t & 63, sc = t >> 6;
        float d = 0.f;
#pragma unroll
        for (int k = 0; k < 8; ++k) {
            int s = sc * 8 + k;
            d += b1[f * 32 + s] * LW[s * 64 + j];
        }
        red[sc * 64 + j] = d;
    }
    {   // frag build (reads LW only)
        int mi = w;
        int col = 32 * (mi & 1) + 8 * (rr >> 2) + 4 * (mi >> 1) + (rr & 3);
        int base = (8 * g) * 64 + col;
        U8 v;
        v.u[0] = cvtpk(LW[base],       LW[base + 64]);
        v.u[1] = cvtpk(LW[base + 128], LW[base + 192]);
        v.u[2] = cvtpk(LW[base + 256], LW[base + 320]);
        v.u[3] = cvtpk(LW[base + 384], LW[base + 448]);
        ((short8*)(ws + OFF_W1F))[((size_t)f * 4 + mi) * 64 + lane] = v.s8;
    }
    __syncthreads();
    if (t < 64) {
        float d = red[t] + red[64 + t] + red[128 + t] + red[192 + t];
        int dst = 32 * ((t >> 2) & 1) + 16 * (t >> 5) + 4 * ((t >> 3) & 3) + (t & 3);
        tab[64 + dst] = -d;
    }
    __syncthreads();

    // ---- phase 2: W2 -> -d2, w2 frag image ----
    *(float4*)&LW[t * 4]        = *(const float4*)&W2f[t * 4];
    *(float4*)&LW[1024 + t * 4] = *(const float4*)&W2f[1024 + t * 4];
    __syncthreads();
    {
        int o = t & 31, hc = t >> 5;
        float d = 0.f;
#pragma unroll
        for (int k = 0; k < 8; ++k) {
            int h = hc * 8 + k;
            d += b2[f * 64 + h] * LW[h * 32 + o];
        }
        red[hc * 32 + o] = d;
    }
    {   // frag build
        int m2 = w >> 1, kc = w & 1;
        int base = (32 * kc + 8 * g) * 32 + 16 * m2 + rr;
        U8 v;
        v.u[0] = cvtpk(LW[base],       LW[base + 32]);
        v.u[1] = cvtpk(LW[base + 64],  LW[base + 96]);
        v.u[2] = cvtpk(LW[base + 128], LW[base + 160]);
        v.u[3] = cvtpk(LW[base + 192], LW[base + 224]);
        ((short8*)(ws + OFF_W2F))[((size_t)f * 4 + m2 * 2 + kc) * 64 + lane] = v.s8;
    }
    __syncthreads();
    if (t < 32) {
        float d = 0.f;
#pragma unroll
        for (int k = 0; k < 8; ++k) d += red[k * 32 + t];
        tab[128 + t] = -d;
    }
}

__device__ __forceinline__ short8 make_hb(float xv, const f32x4& A0, const f32x4& A1,
                                          const f32x4& C0, const f32x4& C1) {
    union { uint32 u[4]; short8 s8; } hb;
    hb.u[0] = cvtpk(clip01(fmaf(xv, A0[0], C0[0])), clip01(fmaf(xv, A0[1], C0[1])));
    hb.u[1] = cvtpk(clip01(fmaf(xv, A0[2], C0[2])), clip01(fmaf(xv, A0[3], C0[3])));
    hb.u[2] = cvtpk(clip01(fmaf(xv, A1[0], C1[0])), clip01(fmaf(xv, A1[1], C1[1])));
    hb.u[3] = cvtpk(clip01(fmaf(xv, A1[2], C1[2])), clip01(fmaf(xv, A1[3], C1[3])));
    return hb.s8;
}
__device__ __forceinline__ short8 packrelu(const f32x4& x, const f32x4& y) {
    union { uint32 u[4]; short8 s8; } r;
    r.u[0] = cvtpk(fmaxf(x[0], 0.f), fmaxf(x[1], 0.f));
    r.u[1] = cvtpk(fmaxf(x[2], 0.f), fmaxf(x[3], 0.f));
    r.u[2] = cvtpk(fmaxf(y[0], 0.f), fmaxf(y[1], 0.f));
    r.u[3] = cvtpk(fmaxf(y[2], 0.f), fmaxf(y[3], 0.f));
    return r.s8;
}

// ---------- K1: main — occupancy-first: 4 features x 256 rows/block, single-chain,
// builtin MFMA (compiler-managed hazards), grid 2048 blocks = 8/CU, LDS-psum epilogue
// (no cross-lane shuffles in the dependent chain; banks (rr*4+g)%32 = 2-way = free) ----------
__global__ __launch_bounds__(256, 4) void nam_main(
    const float* __restrict__ x, const float* __restrict__ Wl,
    const char* __restrict__ ws, float* __restrict__ fout, float* __restrict__ part)
{
    const int fq = blockIdx.y;              // 0..127
    const int f0 = fq * FPB;
    const int rbase = blockIdx.x * RB;
    const int t = threadIdx.x;
    const int w = t >> 6, lane = t & 63;
    const int g = lane >> 4, rr = lane & 15;
    const int f = f0 + w;

    __shared__ float sx[FPB * RB];          // [fi][256] 4 KB (reused for results)
    __shared__ float psum[FPB * RB * 4];    // [fi][row][g] 16 KB

    // stage x (natural layout): 1 float4 per thread
    {
        float4 v = *(const float4*)(x + (size_t)(rbase + t) * F + f0);
        sx[0 * RB + t] = v.x; sx[1 * RB + t] = v.y;
        sx[2 * RB + t] = v.z; sx[3 * RB + t] = v.w;
    }

    // per-wave weight fragments + tables (aligned vector loads from L2)
    const short8* w1img = (const short8*)(ws + OFF_W1F);
    const short8* w2img = (const short8*)(ws + OFF_W2F);
    short8 w1f[4], w2f[2][2];
#pragma unroll
    for (int mi = 0; mi < 4; ++mi) w1f[mi] = w1img[((size_t)f * 4 + mi) * 64 + lane];
#pragma unroll
    for (int m2 = 0; m2 < 2; ++m2)
#pragma unroll
        for (int kc = 0; kc < 2; ++kc)
            w2f[m2][kc] = w2img[((size_t)f * 4 + m2 * 2 + kc) * 64 + lane];

    const f32x4* tabv = (const f32x4*)((const float*)(ws + OFF_TAB) + (size_t)f * 160);
    f32x4 A0 = tabv[2 * g], A1 = tabv[2 * g + 1];
    f32x4 C0 = tabv[8 + 2 * g], C1 = tabv[8 + 2 * g + 1];
    f32x4 nd1[4];
#pragma unroll
    for (int mi = 0; mi < 4; ++mi) nd1[mi] = tabv[16 + 4 * mi + g];
    f32x4 nd2[2];
#pragma unroll
    for (int m2 = 0; m2 < 2; ++m2) nd2[m2] = tabv[32 + 4 * m2 + g];
    f32x4 wl0 = *(const f32x4*)(Wl + f * 32 + 4 * g);
    f32x4 wl1 = *(const f32x4*)(Wl + f * 32 + 16 + 4 * g);

    __syncthreads();

    const float* sxf = sx + w * RB;
    float* psw = psum + w * (RB * 4);       // this wave's [row][g] slab

    // 16 tiles, single chain each — minimal live state, TLP hides the chain
    for (int k = 0; k < 16; ++k) {
        float xv = sxf[16 * k + rr];
        short8 hb = make_hb(xv, A0, A1, C0, C1);

        f32x4 a0 = __builtin_amdgcn_mfma_f32_16x16x32_bf16(w1f[0], hb, nd1[0], 0, 0, 0);
        f32x4 a1 = __builtin_amdgcn_mfma_f32_16x16x32_bf16(w1f[1], hb, nd1[1], 0, 0, 0);
        f32x4 a2 = __builtin_amdgcn_mfma_f32_16x16x32_bf16(w1f[2], hb, nd1[2], 0, 0, 0);
        f32x4 a3 = __builtin_amdgcn_mfma_f32_16x16x32_bf16(w1f[3], hb, nd1[3], 0, 0, 0);

        short8 r0 = packrelu(a0, a2);
        short8 r1 = packrelu(a1, a3);

        f32x4 c0 = __builtin_amdgcn_mfma_f32_16x16x32_bf16(w2f[0][0], r0, nd2[0], 0, 0, 0);
        c0 = __builtin_amdgcn_mfma_f32_16x16x32_bf16(w2f[0][1], r1, c0, 0, 0, 0);
        f32x4 c1 = __builtin_amdgcn_mfma_f32_16x16x32_bf16(w2f[1][0], r0, nd2[1], 0, 0, 0);
        c1 = __builtin_amdgcn_mfma_f32_16x16x32_bf16(w2f[1][1], r1, c1, 0, 0, 0);

        float p = 0.f;
#pragma unroll
        for (int r = 0; r < 4; ++r) {
            p = fmaf(fmaxf(c0[r], 0.f), wl0[r], p);
            p = fmaf(fmaxf(c1[r], 0.f), wl1[r], p);
        }
        psw[(16 * k + rr) * 4 + g] = p;     // bank (rr*4+g)%32: 2-way alias = free
    }

    // per-wave g-reduce of own slab (ds ops within a wave are ordered; no sync needed)
#pragma unroll
    for (int i = 0; i < 4; ++i) {
        int row = i * 64 + lane;
        f32x4 v = *(const f32x4*)&psw[row * 4];
        ((float*)sx)[w * RB + row] = (v[0] + v[1]) + (v[2] + v[3]);
    }

    __syncthreads();

    // coalesced fout write (natural layout) + per-(fq,row) partial sums
    {
        int r = t;
        float v0 = sx[0 * RB + r], v1 = sx[1 * RB + r];
        float v2 = sx[2 * RB + r], v3 = sx[3 * RB + r];
        *(float4*)(fout + (size_t)(rbase + r) * F + f0) = make_float4(v0, v1, v2, v3);
        part[(size_t)fq * NB + rbase + r] = (v0 + v1) + (v2 + v3);
    }
}

// ---------- K2: out0[r] = bias + sum of 128 partials ----------
__global__ __launch_bounds__(256) void nam_sum(const float* __restrict__ part,
                                               const float* __restrict__ ob,
                                               float* __restrict__ out0) {
    int r = blockIdx.x * 256 + threadIdx.x;
    float s = ob[0];
#pragma unroll 8
    for (int q = 0; q < NFQ; ++q) s += part[(size_t)q * NB + r];
    out0[r] = s;
}

// ================= fallback (round-1 VALU kernel, used if ws too small) =================
namespace fbk { constexpr int S = 32, H1 = 64, H2 = 32, BLK = 256, ROWS = 2, P1 = 36; }
__global__ __launch_bounds__(256, 2) void fb_main(
    const float* __restrict__ x,  const float* __restrict__ W0,
    const float* __restrict__ b0, const float* __restrict__ W1,
    const float* __restrict__ b1, const float* __restrict__ W2,
    const float* __restrict__ b2, const float* __restrict__ Wl,
    float* __restrict__ fout) {
    using namespace fbk;
    const int f = blockIdx.y;
    const int bbase = blockIdx.x * (BLK * ROWS);
    const int t = threadIdx.x;
    __shared__ float W0e[S * S];
    __shared__ float W1t[H1 * P1];
    __shared__ float W2l[H1 * H2];
    __shared__ float sb0[S], sb1[S], sb2[H1];
    __shared__ float sA[S], sC[S], sd1[H1], sd2[H2], sWl[H2];
    {
        float4 wv = *reinterpret_cast<const float4*>(W0 + (size_t)f * S * S + t * 4);
        W0e[t * 4 + 0] = expf(wv.x); W0e[t * 4 + 1] = expf(wv.y);
        W0e[t * 4 + 2] = expf(wv.z); W0e[t * 4 + 3] = expf(wv.w);
    }
    if (t < S) sb0[t] = b0[f * S + t];
    else if (t < 2 * S) sb1[t - S] = b1[f * S + (t - S)];
    else if (t < 2 * S + H1) sb2[t - 2 * S] = b2[f * H1 + (t - 2 * S)];
    else if (t < 2 * S + H1 + H2) sWl[t - 2 * S - H1] = Wl[f * H2 + (t - 2 * S - H1)];
#pragma unroll
    for (int k = 0; k < (S * H1) / BLK; ++k) {
        int i = t + BLK * k; int s = i >> 6, j = i & 63;
        W1t[j * P1 + s] = W1[(size_t)f * S * H1 + i];
    }
#pragma unroll
    for (int k = 0; k < (H1 * H2) / BLK; ++k) {
        int i = t + BLK * k; W2l[i] = W2[(size_t)f * H1 * H2 + i];
    }
    __syncthreads();
    if (t < S) {
        int j = t; float a = 0.f, c = 0.f;
#pragma unroll
        for (int s = 0; s < S; ++s) { float e = W0e[s * S + j]; a += e; c += sb0[s] * e; }
        sA[j] = a; sC[j] = c;
    } else if (t >= 64 && t < 64 + H1) {
        int j = t - 64; float d = 0.f;
#pragma unroll
        for (int s = 0; s < S; ++s) d += sb1[s] * W1t[j * P1 + s];
        sd1[j] = d;
    } else if (t >= 128 && t < 128 + H2) {
        int o = t - 128; float d = 0.f;
#pragma unroll
        for (int h = 0; h < H1; ++h) d += sb2[h] * W2l[h * H2 + o];
        sd2[o] = d;
    }
    __syncthreads();
    const int ra = bbase + t, rb = bbase + BLK + t;
    const float xa = x[(size_t)ra * F + f], xb = x[(size_t)rb * F + f];
    float h0a[S], h0b[S];
#pragma unroll
    for (int j = 0; j < S; ++j) {
        float A = sA[j], C = sC[j];
        h0a[j] = fminf(fmaxf(fmaf(xa, A, -C), 0.f), 1.f);
        h0b[j] = fminf(fmaxf(fmaf(xb, A, -C), 0.f), 1.f);
    }
    float acc2a[H2], acc2b[H2];
#pragma unroll
    for (int o = 0; o < H2; ++o) { float d = sd2[o]; acc2a[o] = -d; acc2b[o] = -d; }
#pragma unroll 2
    for (int j = 0; j < H1; ++j) {
        float wr[S];
#pragma unroll
        for (int q = 0; q < S / 4; ++q)
            *reinterpret_cast<float4*>(&wr[4 * q]) = reinterpret_cast<const float4*>(&W1t[j * P1])[q];
        float d1j = sd1[j];
        float pa0 = -d1j, pa1 = 0.f, pb0 = -d1j, pb1 = 0.f;
#pragma unroll
        for (int s = 0; s < S; s += 2) {
            pa0 = fmaf(h0a[s], wr[s], pa0); pb0 = fmaf(h0b[s], wr[s], pb0);
            pa1 = fmaf(h0a[s + 1], wr[s + 1], pa1); pb1 = fmaf(h0b[s + 1], wr[s + 1], pb1);
        }
        float h1a = fmaxf(pa0 + pa1, 0.f), h1b = fmaxf(pb0 + pb1, 0.f);
        float w2r[H2];
#pragma unroll
        for (int q = 0; q < H2 / 4; ++q)
            *reinterpret_cast<float4*>(&w2r[4 * q]) = reinterpret_cast<const float4*>(&W2l[j * H2])[q];
#pragma unroll
        for (int o = 0; o < H2; ++o) {
            acc2a[o] = fmaf(h1a, w2r[o], acc2a[o]); acc2b[o] = fmaf(h1b, w2r[o], acc2b[o]);
        }
    }
    float outa = 0.f, outb = 0.f;
#pragma unroll
    for (int o = 0; o < H2; ++o) {
        outa = fmaf(fmaxf(acc2a[o], 0.f), sWl[o], outa);
        outb = fmaf(fmaxf(acc2b[o], 0.f), sWl[o], outb);
    }
    fout[(size_t)ra * F + f] = outa;
    fout[(size_t)rb * F + f] = outb;
}
__global__ __launch_bounds__(256) void fb_rowsum(
    const float* __restrict__ fout, const float* __restrict__ out_bias,
    float* __restrict__ out0) {
    const int wave = threadIdx.x >> 6, lane = threadIdx.x & 63;
    const int b = blockIdx.x * 4 + wave;
    float s = 0.f;
#pragma unroll
    for (int k = 0; k < F / 64; ++k) s += fout[(size_t)b * F + k * 64 + lane];
#pragma unroll
    for (int off = 32; off; off >>= 1) s += __shfl_down(s, off, 64);
    if (lane == 0) out0[b] = s + out_bias[0];
}

extern "C" void kernel_launch(void* const* d_in, const int* in_sizes, int n_in,
                              void* d_out, int out_size, void* d_ws, size_t ws_size,
                              hipStream_t stream) {
    const float* x  = (const float*)d_in[0];
    const float* W0 = (const float*)d_in[1];
    const float* b0 = (const float*)d_in[2];
    const float* W1 = (const float*)d_in[3];
    const float* b1 = (const float*)d_in[4];
    const float* W2 = (const float*)d_in[5];
    const float* b2 = (const float*)d_in[6];
    const float* Wl = (const float*)d_in[7];
    const float* ob = (const float*)d_in[8];

    float* out0 = (float*)d_out;      // (B,)
    float* fout = out0 + NB;          // (B,F)

    if (ws_size >= WS_NEED) {
        char* ws = (char*)d_ws;
        float* part = (float*)(ws + OFF_PART);
        nam_prep<<<F, 256, 0, stream>>>(W0, b0, W1, b1, W2, b2, ws);
        nam_main<<<dim3(NB / RB, NFQ), 256, 0, stream>>>(x, Wl, ws, fout, part);
        nam_sum <<<NB / 256, 256, 0, stream>>>(part, ob, out0);
    } else {
        dim3 grid(NB / (fbk::BLK * fbk::ROWS), F);
        fb_main<<<grid, fbk::BLK, 0, stream>>>(x, W0, b0, W1, b1, W2, b2, Wl, fout);
        fb_rowsum<<<NB / 4, 256, 0, stream>>>(fout, ob, out0);
    }
}